// Round 11
// baseline (168.406 us; speedup 1.0000x reference)
//
#include <hip/hip_runtime.h>
#include <hip/hip_bf16.h>

#define BS 4
#define L 2048
#define H 12
#define HD 64
#define R 16
#define HID 768
#define MARGIN 0.02f
#define FIXCAP 16384
#define FIXGRID 1024
// M = BS*L = 8192, N = 768, K = 768

typedef __attribute__((ext_vector_type(8))) short s8v;   // 8 bf16 (4 VGPRs)
typedef __attribute__((ext_vector_type(4))) float f32x4;

static __device__ __forceinline__ unsigned short f2bf_bits(float f) {
    __hip_bfloat16 h = __float2bfloat16(f);
    return *reinterpret_cast<unsigned short*>(&h);
}

// ---------------------------------------------------------------------------
// Prep: both W (k,n) fp32 -> Wt (n,k) bf16 transposes; block 0 zeroes fixcnt.
// ---------------------------------------------------------------------------
__global__ __launch_bounds__(256) void prep_kernel(
    const float* __restrict__ K1w, const float* __restrict__ V1w,
    __hip_bfloat16* __restrict__ WtK, __hip_bfloat16* __restrict__ WtV,
    int* __restrict__ fixcnt)
{
    if (blockIdx.x == 0 && threadIdx.x == 0) *fixcnt = 0;
    const int t = blockIdx.x;
    const int z = t / 576, rem = t % 576;
    const float* in = z ? V1w : K1w;
    __hip_bfloat16* out = z ? WtV : WtK;
    __shared__ float s[32][33];
    const int c = threadIdx.x & 31, r8 = threadIdx.x >> 5;
    const int kt = (rem / 24) * 32, nt = (rem % 24) * 32;
#pragma unroll
    for (int rr = 0; rr < 4; ++rr) {
        int k = r8 + rr * 8;
        s[k][c] = in[(size_t)(kt + k) * HID + nt + c];
    }
    __syncthreads();
#pragma unroll
    for (int rr = 0; rr < 4; ++rr) {
        int n = r8 + rr * 8;
        out[(size_t)(nt + n) * HID + kt + c] = __float2bfloat16(s[c][n]);
    }
}

// ---------------------------------------------------------------------------
// Fused dual GEMM v4 (unchanged from R10): bf16 MFMA, 128x128 tile, BK=32,
// register double-buffer prefetch, in-register fp32->bf16 A conversion,
// XOR chunk swizzle (0 bank conflicts, validated R8).
// ---------------------------------------------------------------------------
__global__ __launch_bounds__(256) void gemm_fused(
    const float* __restrict__ A,             // (8192, 768) fp32 hs
    const __hip_bfloat16* __restrict__ WtK,  // (768, 768) = K1_w^T bf16
    const __hip_bfloat16* __restrict__ WtV,  // (768, 768) = V1_w^T bf16
    const float* __restrict__ K1b,
    const float* __restrict__ V1b,
    const float* __restrict__ RH,            // (H*HD) flat
    float* __restrict__ dots,                // (BS*H, L) fp32
    int* __restrict__ fixlist,               // packed row*16+head
    int* __restrict__ fixcnt,
    __hip_bfloat16* __restrict__ C)          // (8192, 768) relu'd V1
{
    __shared__ alignas(16) __hip_bfloat16 As[128 * 32];
    __shared__ alignas(16) __hip_bfloat16 Bs[128 * 32];

    const int tid = threadIdx.x;
    const bool isV = blockIdx.y < 6;
    const int m0 = blockIdx.x * 128;
    const int n0 = (isV ? blockIdx.y : blockIdx.y - 6) * 128;
    const __hip_bfloat16* Bt = isV ? WtV : WtK;

    const int wid = tid >> 6, lane = tid & 63;
    const int quad = lane >> 4, lm = lane & 15;
    const int wm = wid & 1, wn = wid >> 1;

    const int r0 = tid >> 2,        c0 = tid & 3;
    const int r1 = (tid + 256) >> 2, c1 = tid & 3;
    const int p0 = c0 ^ ((r0 >> 1) & 3);
    const int p1 = c1 ^ ((r1 >> 1) & 3);

    const float* gA0 = A + (size_t)(m0 + r0) * HID + c0 * 8;
    const float* gA1 = A + (size_t)(m0 + r1) * HID + c1 * 8;
    const __hip_bfloat16* gB0 = Bt + (size_t)(n0 + r0) * HID + c0 * 8;
    const __hip_bfloat16* gB1 = Bt + (size_t)(n0 + r1) * HID + c1 * 8;
    uint4* wA0 = (uint4*)&As[r0 * 32 + p0 * 8];
    uint4* wA1 = (uint4*)&As[r1 * 32 + p1 * 8];
    uint4* wB0 = (uint4*)&Bs[r0 * 32 + p0 * 8];
    uint4* wB1 = (uint4*)&Bs[r1 * 32 + p1 * 8];

    const int fsw = (lm >> 1) & 3;
    const __hip_bfloat16* pA = &As[(wm * 64 + lm) * 32 + ((quad ^ fsw) * 8)];
    const __hip_bfloat16* pB = &Bs[(wn * 64 + lm) * 32 + ((quad ^ fsw) * 8)];

    f32x4 acc[4][4] = {};

    float4 a00 = *(const float4*)gA0, a01 = *(const float4*)(gA0 + 4);
    float4 a10 = *(const float4*)gA1, a11 = *(const float4*)(gA1 + 4);
    uint4  b0  = *(const uint4*)gB0,  b1  = *(const uint4*)gB1;
    gA0 += 32; gA1 += 32; gB0 += 32; gB1 += 32;

    for (int it = 0; it < HID / 32; ++it) {
        union { unsigned short s[8]; uint4 v; } u0, u1;
        u0.s[0] = f2bf_bits(a00.x); u0.s[1] = f2bf_bits(a00.y);
        u0.s[2] = f2bf_bits(a00.z); u0.s[3] = f2bf_bits(a00.w);
        u0.s[4] = f2bf_bits(a01.x); u0.s[5] = f2bf_bits(a01.y);
        u0.s[6] = f2bf_bits(a01.z); u0.s[7] = f2bf_bits(a01.w);
        u1.s[0] = f2bf_bits(a10.x); u1.s[1] = f2bf_bits(a10.y);
        u1.s[2] = f2bf_bits(a10.z); u1.s[3] = f2bf_bits(a10.w);
        u1.s[4] = f2bf_bits(a11.x); u1.s[5] = f2bf_bits(a11.y);
        u1.s[6] = f2bf_bits(a11.z); u1.s[7] = f2bf_bits(a11.w);
        *wA0 = u0.v; *wA1 = u1.v;
        *wB0 = b0;   *wB1 = b1;
        __syncthreads();

        if (it + 1 < HID / 32) {
            a00 = *(const float4*)gA0; a01 = *(const float4*)(gA0 + 4);
            a10 = *(const float4*)gA1; a11 = *(const float4*)(gA1 + 4);
            b0  = *(const uint4*)gB0;  b1  = *(const uint4*)gB1;
            gA0 += 32; gA1 += 32; gB0 += 32; gB1 += 32;
        }

        s8v af[4], bf[4];
#pragma unroll
        for (int i = 0; i < 4; ++i) af[i] = *(const s8v*)(pA + i * 16 * 32);
#pragma unroll
        for (int j = 0; j < 4; ++j) bf[j] = *(const s8v*)(pB + j * 16 * 32);
#pragma unroll
        for (int i = 0; i < 4; ++i)
#pragma unroll
            for (int j = 0; j < 4; ++j)
                acc[i][j] = __builtin_amdgcn_mfma_f32_16x16x32_bf16(
                    af[i], bf[j], acc[i][j], 0, 0, 0);
        __syncthreads();
    }

    if (isV) {
#pragma unroll
        for (int i = 0; i < 4; ++i) {
            int row_b = m0 + wm * 64 + i * 16 + quad * 4;
#pragma unroll
            for (int j = 0; j < 4; ++j) {
                int col = n0 + wn * 64 + j * 16 + lm;
                float bsv = V1b[col];
#pragma unroll
                for (int reg = 0; reg < 4; ++reg) {
                    float v = acc[i][j][reg] + bsv;
                    C[(size_t)(row_b + reg) * HID + col] =
                        __float2bfloat16(fmaxf(v, 0.f));
                }
            }
        }
    } else {
        const int head = (n0 >> 6) + wn;
        float bj[4], rj[4];
#pragma unroll
        for (int j = 0; j < 4; ++j) {
            bj[j] = K1b[head * 64 + j * 16 + lm];
            rj[j] = RH[head * 64 + j * 16 + lm];
        }
#pragma unroll
        for (int i = 0; i < 4; ++i) {
            int row0 = m0 + wm * 64 + i * 16 + quad * 4;
#pragma unroll
            for (int reg = 0; reg < 4; ++reg) {
                float p = 0.f;
#pragma unroll
                for (int j = 0; j < 4; ++j)
                    p = fmaf(fmaxf(acc[i][j][reg] + bj[j], 0.f), rj[j], p);
                p += __shfl_xor(p, 1, 64);
                p += __shfl_xor(p, 2, 64);
                p += __shfl_xor(p, 4, 64);
                p += __shfl_xor(p, 8, 64);
                if (lm == 0) {
                    int row = row0 + reg;
                    int b = row >> 11, l = row & (L - 1);
                    dots[((b * H + head) << 11) + l] = p;
                    if (fabsf(p - 0.5f) < MARGIN) {
                        int idx = atomicAdd(fixcnt, 1);
                        if (idx < FIXCAP) fixlist[idx] = row * 16 + head;
                    }
                }
            }
        }
    }
}

// ---------------------------------------------------------------------------
// Fix-up: one block per flagged row (grid-stride over compacted list).
// ---------------------------------------------------------------------------
__global__ __launch_bounds__(256) void fixup_kernel(
    const float* __restrict__ hs,      // (BS*L, 768) fp32
    const float* __restrict__ W,       // (768, 768) K1_w fp32
    const float* __restrict__ bias,
    const float* __restrict__ RH,
    const int* __restrict__ fixlist,
    const int* __restrict__ fixcnt,
    float* __restrict__ dots)
{
    __shared__ float hrow[HID];
    __shared__ float psum[4][64];

    const int tid = threadIdx.x;
    const int n = min(*fixcnt, FIXCAP);

    for (int item = blockIdx.x; item < n; item += FIXGRID) {
        int packed = fixlist[item];
        int row = packed >> 4, head = packed & 15;
        int b = row >> 11, l = row & (L - 1);

#pragma unroll
        for (int i = 0; i < 3; ++i)
            hrow[tid + i * 256] = hs[(size_t)row * HID + tid + i * 256];
        __syncthreads();

        const int d = tid & 63, kq = tid >> 6;
        float a0 = 0.f, a1 = 0.f;
#pragma unroll 8
        for (int i = 0; i < 96; ++i) {
            int k = kq + i * 8;
            a0 = fmaf(W[(size_t)k * HID + head * 64 + d], hrow[k], a0);
            a1 = fmaf(W[(size_t)(k + 4) * HID + head * 64 + d], hrow[k + 4], a1);
        }
        psum[kq][d] = a0 + a1;
        __syncthreads();
        if (tid < 64) {
            float v = psum[0][tid] + psum[1][tid] + psum[2][tid] +
                      psum[3][tid] + bias[head * 64 + tid];
            v = fmaxf(v, 0.f) * RH[head * 64 + tid];
#pragma unroll
            for (int s = 1; s < 64; s <<= 1) v += __shfl_xor(v, s, 64);
            if (tid == 0) dots[((size_t)(b * H + head) << 11) + l] = v;
        }
        __syncthreads();
    }
}

// ---------------------------------------------------------------------------
// Scan: rank/select tables. Pg[bh][l] = # valid in [1..l]; Sg[bh][j] = j-th
// valid index (1-based).
// ---------------------------------------------------------------------------
__global__ __launch_bounds__(256) void scan_kernel(
    const float* __restrict__ dots,   // (BS*H, L)
    unsigned short* __restrict__ Pg,  // (BS*H, L)
    unsigned short* __restrict__ Sg)  // (BS*H, L)
{
    __shared__ int wsum[4];
    const int bh = blockIdx.x;
    const int tid = threadIdx.x;
    const int base = tid * 8;
    const int lane = tid & 63, w = tid >> 6;

    int m[8], c[8];
    int run = 0;
#pragma unroll
    for (int i = 0; i < 8; ++i) {
        int l = base + i;
        m[i] = (l >= 1 && dots[((size_t)bh << 11) + l] > 0.5f) ? 1 : 0;
        run += m[i];
        c[i] = run;
    }
    int sc = run;
#pragma unroll
    for (int s = 1; s < 64; s <<= 1) {
        int v = __shfl_up(sc, s, 64);
        if (lane >= s) sc += v;
    }
    if (lane == 63) wsum[w] = sc;
    __syncthreads();
    int woff = 0;
    for (int i = 0; i < 4; ++i) if (i < w) woff += wsum[i];
    const int ex = woff + sc - run;

    union { unsigned short s[8]; uint4 q; } up;
#pragma unroll
    for (int i = 0; i < 8; ++i) {
        int pc = ex + c[i];
        up.s[i] = (unsigned short)pc;
        if (m[i]) Sg[((size_t)bh << 11) + pc] = (unsigned short)(base + i);
    }
    *(uint4*)&Pg[((size_t)bh << 11) + base] = up.q;
}

// ---------------------------------------------------------------------------
// Gather v5: block = (ltile of 64, bh); 1536 blocks (2x R10's parallelism).
//   phase 1: stage contiguous S-range of V1 row-slices (<=96 rows, 14 KB)
//   phase 2: precompute slot table [64][32] in LDS (kills the 8x-redundant
//            per-d8 index logic of v3)
//   phase 3: per (d8,lg) accumulate 32 slots x 8 elems from LDS; coalesced
//            float4 stores.
// ---------------------------------------------------------------------------
__global__ __launch_bounds__(256) void gather_kernel(
    const __hip_bfloat16* __restrict__ V1,   // (8192, 768) bf16
    const unsigned short* __restrict__ Pg,
    const unsigned short* __restrict__ Sg,
    const float* __restrict__ bw,            // (H, 2R)
    float* __restrict__ out)                 // (8192, 768) fp32
{
    __shared__ __hip_bfloat16 Vs[97 * 72];   // slot pitch 144 B (16B aligned)
    __shared__ unsigned short Ptile[65];     // P[l0-1 .. l0+63]
    __shared__ short slots[64 * 32];         // [ll][r] -> staging slot (0=zero)
    __shared__ float sw[2 * R];
    __shared__ int sT;

    const int bh = blockIdx.y;
    const int b = bh / H, h = bh % H;
    const int l0 = blockIdx.x * 64;
    const int tid = threadIdx.x;

    if (tid < 65) {
        int l = l0 - 1 + tid;
        Ptile[tid] = (l >= 0) ? Pg[((size_t)bh << 11) + l] : (unsigned short)0;
    } else if (tid < 65 + 2 * R) {
        sw[tid - 65] = bw[h * (2 * R) + (tid - 65)];
    } else if (tid == 100) {
        sT = Pg[((size_t)bh << 11) + (L - 1)];
    }
    __syncthreads();

    const int T = sT;
    const int a = max(1, (int)Ptile[1] - (R - 1));
    const int bj = min(T, (int)Ptile[63] + R);
    const int nr = max(0, bj - a + 1);       // <= 95

    // stage V rows: slot 0 = V1[b,0] slice; slots 1..nr = S[a..bj] slices
    const __hip_bfloat16* Vbase = V1 + (size_t)b * L * HID + h * HD;
    for (int it = tid; it < (nr + 1) * 8; it += 256) {
        int slot = it >> 3, oct = it & 7;
        int row = slot ? (int)Sg[((size_t)bh << 11) + a + slot - 1] : 0;
        *(uint4*)&Vs[slot * 72 + oct * 8] =
            *(const uint4*)&Vbase[(size_t)row * HID + oct * 8];
    }
    // slot table: 2048 entries, 8 per thread
#pragma unroll
    for (int q = 0; q < 8; ++q) {
        int i = tid + q * 256;
        int ll = i >> 5, r = i & 31;
        int l = l0 + ll;
        int Pl = Ptile[1 + ll], Plm1 = Ptile[ll];
        int j, ok;
        if (r < R) { j = Pl - r;             ok = (l >= 1) && (j >= 1); }
        else       { j = Plm1 + 1 + (r - R); ok = (l >= 1) && (j <= T); }
        slots[i] = (short)(ok ? (j - a + 1) : 0);
    }
    __syncthreads();

    const int d8 = tid & 7, lg = tid >> 3;   // lg 0..31

#pragma unroll
    for (int li = 0; li < 2; ++li) {
        int ll = lg + 32 * li;               // 0..63
        int l = l0 + ll;
        float acc0 = 0.f, acc1 = 0.f, acc2 = 0.f, acc3 = 0.f;
        float acc4 = 0.f, acc5 = 0.f, acc6 = 0.f, acc7 = 0.f;
#pragma unroll
        for (int r = 0; r < 2 * R; ++r) {
            int slot = slots[ll * 32 + r];   // broadcast within d8 octet
            float wv = sw[r];
            uint4 uv = *(const uint4*)&Vs[slot * 72 + d8 * 8];
            acc0 = fmaf(wv, __uint_as_float(uv.x << 16), acc0);
            acc1 = fmaf(wv, __uint_as_float(uv.x & 0xffff0000u), acc1);
            acc2 = fmaf(wv, __uint_as_float(uv.y << 16), acc2);
            acc3 = fmaf(wv, __uint_as_float(uv.y & 0xffff0000u), acc3);
            acc4 = fmaf(wv, __uint_as_float(uv.z << 16), acc4);
            acc5 = fmaf(wv, __uint_as_float(uv.z & 0xffff0000u), acc5);
            acc6 = fmaf(wv, __uint_as_float(uv.w << 16), acc6);
            acc7 = fmaf(wv, __uint_as_float(uv.w & 0xffff0000u), acc7);
        }
        float* op = &out[((size_t)b * L + l) * HID + h * HD + d8 * 8];
        float4 o0, o1;
        o0.x = acc0; o0.y = acc1; o0.z = acc2; o0.w = acc3;
        o1.x = acc4; o1.y = acc5; o1.z = acc6; o1.w = acc7;
        *(float4*)op = o0;
        *(float4*)(op + 4) = o1;
    }
}

extern "C" void kernel_launch(void* const* d_in, const int* in_sizes, int n_in,
                              void* d_out, int out_size, void* d_ws, size_t ws_size,
                              hipStream_t stream) {
    const float* hs  = (const float*)d_in[0];
    const float* K1w = (const float*)d_in[1];
    const float* K1b = (const float*)d_in[2];
    const float* V1w = (const float*)d_in[3];
    const float* V1b = (const float*)d_in[4];
    const float* RH  = (const float*)d_in[5];
    const float* bw  = (const float*)d_in[6];
    float* out = (float*)d_out;

    // workspace layout (total ~15.8 MB)
    char* ws = (char*)d_ws;
    __hip_bfloat16* WtV = (__hip_bfloat16*)ws;                 // 1,179,648
    __hip_bfloat16* WtK = (__hip_bfloat16*)(ws + 1179648);     // 1,179,648
    __hip_bfloat16* V1  = (__hip_bfloat16*)(ws + 2359296);     // 12,582,912
    float* dots = (float*)(ws + 14942208);                     //   393,216
    unsigned short* Pg = (unsigned short*)(ws + 15335424);     //   196,608
    unsigned short* Sg = (unsigned short*)(ws + 15532032);     //   196,608
    int* fixlist = (int*)(ws + 15728640);                      //    65,536
    int* fixcnt  = (int*)(ws + 15794176);                      //         4

    prep_kernel<<<2 * 24 * 24, 256, 0, stream>>>(K1w, V1w, WtK, WtV, fixcnt);
    gemm_fused<<<dim3(BS * L / 128, 12), 256, 0, stream>>>(
        hs, WtK, WtV, K1b, V1b, RH, dots, fixlist, fixcnt, V1);
    fixup_kernel<<<FIXGRID, 256, 0, stream>>>(hs, K1w, K1b, RH, fixlist, fixcnt, dots);
    scan_kernel<<<BS * H, 256, 0, stream>>>(dots, Pg, Sg);
    gather_kernel<<<dim3(L / 64, BS * H), 256, 0, stream>>>(V1, Pg, Sg, bw, out);
}